// Round 1
// baseline (226.228 us; speedup 1.0000x reference)
//
#include <hip/hip_runtime.h>
#include <hip/hip_bf16.h>
#include <type_traits>

// ---------------------------------------------------------------------------
// Problem constants
//   x: (8,128,128,256) f32   z: (8,64,64,256) f32   mask: (1,8,8,8,256,64) int
//   Wq (256,256) bq(256)  Wkv (256,512) bkv(512)  Wo (256,256) bo(256)
//   rel_table (900,8) f32
//   out: (8,128,128,256) f32
// ---------------------------------------------------------------------------

typedef __attribute__((ext_vector_type(8))) short short8v;     // MFMA bf16 frag (4 VGPR)
typedef __attribute__((ext_vector_type(4))) float f32x4;       // MFMA acc
typedef __attribute__((ext_vector_type(8))) unsigned short ushort8v;
typedef __attribute__((ext_vector_type(4))) unsigned short ushort4v;

#define DEV __device__ __forceinline__

DEV unsigned short f2bf(float f) {               // round-to-nearest-even f32->bf16
    union { float f; unsigned u; } v; v.f = f;
    unsigned r = v.u + 0x7FFFu + ((v.u >> 16) & 1u);
    return (unsigned short)(r >> 16);
}

// ---------------------------------------------------------------------------
// Prep: weights -> bf16 transposed (B^T row-major [N][K]) for MFMA B-operand
// ---------------------------------------------------------------------------
__global__ void prep_weights(const float* __restrict__ Wq, const float* __restrict__ Wkv,
                             const float* __restrict__ Wo,
                             unsigned short* __restrict__ WqT, unsigned short* __restrict__ WkvT,
                             unsigned short* __restrict__ WoT) {
    int idx = blockIdx.x * 256 + threadIdx.x;            // 262144 total
    if (idx < 65536) {                                   // WqT[n][k] = Wq[k][n]
        int n = idx >> 8, k = idx & 255;
        WqT[idx] = f2bf(Wq[k * 256 + n]);
    } else if (idx < 196608) {                           // WkvT[n][k] = Wkv[k][n], n<512
        int i = idx - 65536;
        int n = i >> 8, k = i & 255;
        WkvT[i] = f2bf(Wkv[k * 512 + n]);
    } else {                                             // WoT
        int i = idx - 196608;
        int n = i >> 8, k = i & 255;
        WoT[i] = f2bf(Wo[k * 256 + n]);
    }
}

// bias buffer [head][q(256)][k(64)] f32 from rel_table
__global__ void prep_bias(const float* __restrict__ rel_table, float* __restrict__ biasb) {
    int idx = blockIdx.x * 256 + threadIdx.x;            // 131072 total
    int head = idx >> 14;
    int q = (idx >> 6) & 255;
    int k = idx & 63;
    int qi = q >> 4, qj = q & 15;
    int ki = k >> 3, kj = k & 7;
    int r0 = qi - 2 * ki + 14, r1 = qj - 2 * kj + 14;    // in [0,29]
    biasb[idx] = rel_table[(r0 * 30 + r1) * 8 + head];
}

// ---------------------------------------------------------------------------
// GEMM: C[M][N] = A[M][K] * B + bias.  B given as B^T row-major bf16 [N][K].
// A is f32 (converted on stage) or bf16.  128x128 tile, BK=32, 4 waves (2x2).
// mfma_f32_16x16x32_bf16; A-frag: row=lane&15, k=(lane>>4)*8+j (contig 8);
// B-frag from B^T rows likewise; C/D: col=lane&15, row=(lane>>4)*4+j.
// ---------------------------------------------------------------------------
template <typename InT, bool OUT_BF16>
__global__ __launch_bounds__(256) void gemm_proj(
    const InT* __restrict__ A, const unsigned short* __restrict__ BT,
    const float* __restrict__ bias, void* __restrict__ Cout,
    int M, int N, int K)
{
    __shared__ __align__(16) unsigned short As[128][40];   // pad 32->40: 2-way max
    __shared__ __align__(16) unsigned short Bs[128][40];

    const int tid = threadIdx.x;
    const int mb = blockIdx.y * 128;
    const int nb = blockIdx.x * 128;
    const int w = tid >> 6, lane = tid & 63, lr = lane & 15, lg = lane >> 4;
    const int wm = (w >> 1) * 64, wn = (w & 1) * 64;       // wave 64x64 sub-tile

    f32x4 acc[4][4];
#pragma unroll
    for (int i = 0; i < 4; ++i)
#pragma unroll
        for (int j = 0; j < 4; ++j) acc[i][j] = {0.f, 0.f, 0.f, 0.f};

    for (int kb = 0; kb < K; kb += 32) {
        // ---- stage A tile (128 x 32) ----
        if constexpr (std::is_same<InT, float>::value) {
#pragma unroll
            for (int i = 0; i < 4; ++i) {
                int row = (tid >> 3) + i * 32;
                int c4 = (tid & 7) * 4;
                const float4 v = *reinterpret_cast<const float4*>(
                    &A[(size_t)(mb + row) * K + kb + c4]);
                ushort4v u = { f2bf(v.x), f2bf(v.y), f2bf(v.z), f2bf(v.w) };
                *reinterpret_cast<ushort4v*>(&As[row][c4]) = u;
            }
        } else {
#pragma unroll
            for (int i = 0; i < 2; ++i) {
                int flat = tid + i * 256;
                int row = flat >> 2, c8 = (flat & 3) * 8;
                ushort8v v = *reinterpret_cast<const ushort8v*>(
                    &A[(size_t)(mb + row) * K + kb + c8]);
                *reinterpret_cast<ushort8v*>(&As[row][c8]) = v;
            }
        }
        // ---- stage B tile (128 x 32) from B^T ----
#pragma unroll
        for (int i = 0; i < 2; ++i) {
            int flat = tid + i * 256;
            int row = flat >> 2, c8 = (flat & 3) * 8;
            ushort8v v = *reinterpret_cast<const ushort8v*>(
                &BT[(size_t)(nb + row) * K + kb + c8]);
            *reinterpret_cast<ushort8v*>(&Bs[row][c8]) = v;
        }
        __syncthreads();

        short8v af[4], bfr[4];
#pragma unroll
        for (int mt = 0; mt < 4; ++mt)
            af[mt] = *reinterpret_cast<const short8v*>(&As[wm + mt * 16 + lr][lg * 8]);
#pragma unroll
        for (int nt = 0; nt < 4; ++nt)
            bfr[nt] = *reinterpret_cast<const short8v*>(&Bs[wn + nt * 16 + lr][lg * 8]);
#pragma unroll
        for (int mt = 0; mt < 4; ++mt)
#pragma unroll
            for (int nt = 0; nt < 4; ++nt)
                acc[mt][nt] = __builtin_amdgcn_mfma_f32_16x16x32_bf16(
                    af[mt], bfr[nt], acc[mt][nt], 0, 0, 0);
        __syncthreads();
    }

    // ---- epilogue ----
#pragma unroll
    for (int mt = 0; mt < 4; ++mt)
#pragma unroll
        for (int nt = 0; nt < 4; ++nt)
#pragma unroll
            for (int j = 0; j < 4; ++j) {
                int row = mb + wm + mt * 16 + lg * 4 + j;
                int col = nb + wn + nt * 16 + lr;
                float v = acc[mt][nt][j] + bias[col];
                if constexpr (OUT_BF16)
                    ((unsigned short*)Cout)[(size_t)row * N + col] = f2bf(v);
                else
                    ((float*)Cout)[(size_t)row * N + col] = v;
            }
}

// ---------------------------------------------------------------------------
// Fused window attention. One block = (b, window, head). 256 threads, 4 waves,
// each wave owns 64 q-rows. S=QK^T (256x64, K=32 -> 1 MFMA per 16x16 tile),
// bias+mask+softmax (16-lane shfl reduce), O=PV (256x32). Output written
// in-place into Qbuf (block tile is disjoint across blocks).
// Shifted windows folded into index math: q row (16wi+li+8)&127, k row (8wi+ki+4)&63.
// ---------------------------------------------------------------------------
__global__ __launch_bounds__(256) void win_attn(
    unsigned short* __restrict__ Qbuf,        // [8*128*128, 256] bf16 (in/out)
    const unsigned short* __restrict__ KVbuf, // [8*64*64, 512] bf16 (K cols 0-255, V 256-511)
    const int* __restrict__ mask,             // [8,8,8,256,64]
    const float* __restrict__ biasb)          // [8,256,64]
{
    __shared__ __align__(16) unsigned char sQP[256 * 144];  // Qs[256][40] / Ps[256][72] overlap
    __shared__ __align__(16) unsigned short Ks[64][40];
    __shared__ __align__(16) unsigned short Vt[32][72];     // V transposed: [dk][key]
    auto Qs = reinterpret_cast<unsigned short(*)[40]>(sQP);
    auto Ps = reinterpret_cast<unsigned short(*)[72]>(sQP);

    const int tid = threadIdx.x;
    const int win = blockIdx.x, head = blockIdx.y, b = blockIdx.z;
    const int wi = win >> 3, wj = win & 7;

    // ---- stage Q: one q-row per thread (64B) ----
    {
        int li = tid >> 4, lj = tid & 15;
        int gr = (wi * 16 + li + 8) & 127;
        int gc = (wj * 16 + lj + 8) & 127;
        const unsigned short* src =
            Qbuf + ((size_t)(b * 16384 + gr * 128 + gc)) * 256 + head * 32;
#pragma unroll
        for (int c = 0; c < 4; ++c)
            *reinterpret_cast<ushort8v*>(&Qs[tid][c * 8]) =
                *reinterpret_cast<const ushort8v*>(src + c * 8);
    }
    // ---- stage K (threads 0-63) and V transposed (threads 64-127) ----
    if (tid < 64) {
        int ki = tid >> 3, kj = tid & 7;
        int kr = (wi * 8 + ki + 4) & 63;
        int kc = (wj * 8 + kj + 4) & 63;
        const unsigned short* src =
            KVbuf + ((size_t)(b * 4096 + kr * 64 + kc)) * 512 + head * 32;
#pragma unroll
        for (int c = 0; c < 4; ++c)
            *reinterpret_cast<ushort8v*>(&Ks[tid][c * 8]) =
                *reinterpret_cast<const ushort8v*>(src + c * 8);
    } else if (tid < 128) {
        int key = tid - 64;
        int ki = key >> 3, kj = key & 7;
        int kr = (wi * 8 + ki + 4) & 63;
        int kc = (wj * 8 + kj + 4) & 63;
        const unsigned short* src =
            KVbuf + ((size_t)(b * 4096 + kr * 64 + kc)) * 512 + 256 + head * 32;
#pragma unroll
        for (int c = 0; c < 4; ++c) {
            ushort8v v = *reinterpret_cast<const ushort8v*>(src + c * 8);
#pragma unroll
            for (int e = 0; e < 8; ++e) Vt[c * 8 + e][key] = v[e];
        }
    }
    __syncthreads();

    const int w = tid >> 6, lane = tid & 63, lr = lane & 15, lg = lane >> 4;
    const int qb = w * 64;

    // ---- S = Q K^T : per wave 4 m-tiles x 4 n-tiles, single K=32 step ----
    short8v qf[4], kf[4];
#pragma unroll
    for (int mt = 0; mt < 4; ++mt)
        qf[mt] = *reinterpret_cast<const short8v*>(&Qs[qb + mt * 16 + lr][lg * 8]);
#pragma unroll
    for (int nt = 0; nt < 4; ++nt)
        kf[nt] = *reinterpret_cast<const short8v*>(&Ks[nt * 16 + lr][lg * 8]);

    f32x4 s[4][4];
#pragma unroll
    for (int mt = 0; mt < 4; ++mt)
#pragma unroll
        for (int nt = 0; nt < 4; ++nt) s[mt][nt] = {0.f, 0.f, 0.f, 0.f};
#pragma unroll
    for (int mt = 0; mt < 4; ++mt)
#pragma unroll
        for (int nt = 0; nt < 4; ++nt)
            s[mt][nt] = __builtin_amdgcn_mfma_f32_16x16x32_bf16(qf[mt], kf[nt], s[mt][nt], 0, 0, 0);

    __syncthreads();   // all Qs reads done; Ps may now overwrite the region

    // ---- scale + bias + mask + softmax (row = 16 lanes x 4 n-tiles) ----
    const float scale = 0.17677669529663687f;   // 1/sqrt(32)
#pragma unroll
    for (int mt = 0; mt < 4; ++mt) {
#pragma unroll
        for (int j = 0; j < 4; ++j) {
            int q = qb + mt * 16 + lg * 4 + j;
            float v[4];
            float m = -3.0e38f;
#pragma unroll
            for (int nt = 0; nt < 4; ++nt) {
                int key = nt * 16 + lr;
                float bi = biasb[(head * 256 + q) * 64 + key];
                int mk = mask[(((head * 64 + win) * 256 + q) * 64) + key];
                float sv = s[mt][nt][j] * scale + bi;
                if (mk) sv = -1.0e9f;
                v[nt] = sv;
                m = fmaxf(m, sv);
            }
#pragma unroll
            for (int d = 1; d < 16; d <<= 1) m = fmaxf(m, __shfl_xor(m, d, 64));
            float sum = 0.f;
#pragma unroll
            for (int nt = 0; nt < 4; ++nt) { v[nt] = __expf(v[nt] - m); sum += v[nt]; }
#pragma unroll
            for (int d = 1; d < 16; d <<= 1) sum += __shfl_xor(sum, d, 64);
            float inv = 1.0f / sum;
#pragma unroll
            for (int nt = 0; nt < 4; ++nt)
                Ps[q][nt * 16 + lr] = f2bf(v[nt] * inv);
        }
    }
    // wave reads only its own Ps rows -> same-wave LDS ordering suffices

    // ---- O = P V : K=64 in 2 chunks; V^T gives B-frags contiguous in key ----
    f32x4 o[4][2];
#pragma unroll
    for (int mt = 0; mt < 4; ++mt)
#pragma unroll
        for (int nt = 0; nt < 2; ++nt) o[mt][nt] = {0.f, 0.f, 0.f, 0.f};
#pragma unroll
    for (int kc = 0; kc < 2; ++kc) {
        short8v pf[4], vf[2];
#pragma unroll
        for (int mt = 0; mt < 4; ++mt)
            pf[mt] = *reinterpret_cast<const short8v*>(&Ps[qb + mt * 16 + lr][kc * 32 + lg * 8]);
#pragma unroll
        for (int nt = 0; nt < 2; ++nt)
            vf[nt] = *reinterpret_cast<const short8v*>(&Vt[nt * 16 + lr][kc * 32 + lg * 8]);
#pragma unroll
        for (int mt = 0; mt < 4; ++mt)
#pragma unroll
            for (int nt = 0; nt < 2; ++nt)
                o[mt][nt] = __builtin_amdgcn_mfma_f32_16x16x32_bf16(pf[mt], vf[nt], o[mt][nt], 0, 0, 0);
    }

    // ---- store O in-place into Qbuf (merge + unroll folded into index) ----
#pragma unroll
    for (int mt = 0; mt < 4; ++mt)
#pragma unroll
        for (int nt = 0; nt < 2; ++nt)
#pragma unroll
            for (int j = 0; j < 4; ++j) {
                int q = qb + mt * 16 + lg * 4 + j;
                int li = q >> 4, lj = q & 15;
                int gr = (wi * 16 + li + 8) & 127;
                int gc = (wj * 16 + lj + 8) & 127;
                int dk = nt * 16 + lr;
                Qbuf[((size_t)(b * 16384 + gr * 128 + gc)) * 256 + head * 32 + dk] =
                    f2bf(o[mt][nt][j]);
            }
}

// ---------------------------------------------------------------------------
extern "C" void kernel_launch(void* const* d_in, const int* in_sizes, int n_in,
                              void* d_out, int out_size, void* d_ws, size_t ws_size,
                              hipStream_t stream) {
    const float* x    = (const float*)d_in[0];
    const float* z    = (const float*)d_in[1];
    const int*   mask = (const int*)d_in[2];
    const float* Wq   = (const float*)d_in[3];
    const float* bq   = (const float*)d_in[4];
    const float* Wkv  = (const float*)d_in[5];
    const float* bkv  = (const float*)d_in[6];
    const float* Wo   = (const float*)d_in[7];
    const float* bo   = (const float*)d_in[8];
    const float* rel  = (const float*)d_in[9];
    float* out = (float*)d_out;

    // workspace layout (~102 MB)
    char* ws = (char*)d_ws;
    unsigned short* Qbuf  = (unsigned short*)(ws);                    // 67,108,864 B
    unsigned short* KVbuf = (unsigned short*)(ws + 67108864);         // 33,554,432 B
    unsigned short* WqT   = (unsigned short*)(ws + 100663296);        //    131,072 B
    unsigned short* WkvT  = (unsigned short*)(ws + 100794368);        //    262,144 B
    unsigned short* WoT   = (unsigned short*)(ws + 101056512);        //    131,072 B
    float*          biasb = (float*)(ws + 101187584);                 //    524,288 B

    prep_weights<<<1024, 256, 0, stream>>>(Wq, Wkv, Wo, WqT, WkvT, WoT);
    prep_bias<<<512, 256, 0, stream>>>(rel, biasb);

    // Q = x @ Wq + bq  -> bf16 [131072, 256]
    gemm_proj<float, true><<<dim3(2, 1024), 256, 0, stream>>>(
        x, WqT, bq, (void*)Qbuf, 131072, 256, 256);
    // KV = z @ Wkv + bkv -> bf16 [32768, 512]
    gemm_proj<float, true><<<dim3(4, 256), 256, 0, stream>>>(
        z, WkvT, bkv, (void*)KVbuf, 32768, 512, 256);
    // fused window attention (in-place into Qbuf)
    win_attn<<<dim3(64, 8, 8), 256, 0, stream>>>(Qbuf, KVbuf, mask, biasb);
    // out = attn @ Wo + bo -> f32
    gemm_proj<unsigned short, false><<<dim3(2, 1024), 256, 0, stream>>>(
        Qbuf, WoT, bo, (void*)out, 131072, 256, 256);
}

// Round 2
// 222.094 us; speedup vs baseline: 1.0186x; 1.0186x over previous
//
#include <hip/hip_runtime.h>
#include <hip/hip_bf16.h>
#include <type_traits>

// ---------------------------------------------------------------------------
// Problem constants
//   x: (8,128,128,256) f32   z: (8,64,64,256) f32   mask: (1,8,8,8,256,64) int
//   Wq (256,256) bq(256)  Wkv (256,512) bkv(512)  Wo (256,256) bo(256)
//   rel_table (900,8) f32   out: (8,128,128,256) f32
// ---------------------------------------------------------------------------

typedef __attribute__((ext_vector_type(8))) short short8v;     // MFMA bf16 frag (4 VGPR)
typedef __attribute__((ext_vector_type(4))) float f32x4;       // MFMA acc
typedef __attribute__((ext_vector_type(8))) unsigned short ushort8v;
typedef __attribute__((ext_vector_type(4))) unsigned short ushort4v;

#define DEV __device__ __forceinline__

DEV unsigned short f2bf(float f) {               // round-to-nearest-even f32->bf16
    union { float f; unsigned u; } v; v.f = f;
    unsigned r = v.u + 0x7FFFu + ((v.u >> 16) & 1u);
    return (unsigned short)(r >> 16);
}

#define ATT_SCALE 0.17677669529663687f           // 1/sqrt(32)

// ---------------------------------------------------------------------------
// Prep: weights -> bf16 transposed (B^T row-major [N][K]); Wq pre-scaled by
// 1/sqrt(dk) so attention needs no per-element scale.
// ---------------------------------------------------------------------------
__global__ void prep_weights(const float* __restrict__ Wq, const float* __restrict__ Wkv,
                             const float* __restrict__ Wo,
                             unsigned short* __restrict__ WqT, unsigned short* __restrict__ WkvT,
                             unsigned short* __restrict__ WoT) {
    int idx = blockIdx.x * 256 + threadIdx.x;            // 262144 total
    if (idx < 65536) {                                   // WqT[n][k] = Wq[k][n] * scale
        int n = idx >> 8, k = idx & 255;
        WqT[idx] = f2bf(Wq[k * 256 + n] * ATT_SCALE);
    } else if (idx < 196608) {                           // WkvT[n][k] = Wkv[k][n], n<512
        int i = idx - 65536;
        int n = i >> 8, k = i & 255;
        WkvT[i] = f2bf(Wkv[k * 512 + n]);
    } else {                                             // WoT
        int i = idx - 196608;
        int n = i >> 8, k = i & 255;
        WoT[i] = f2bf(Wo[k * 256 + n]);
    }
}

// bias buffer [head][q(256)][k(64)] f32 from rel_table; also scaled bq copy
__global__ void prep_bias(const float* __restrict__ rel_table, const float* __restrict__ bq,
                          float* __restrict__ biasb, float* __restrict__ bqs) {
    int idx = blockIdx.x * 256 + threadIdx.x;            // 131072 bias + 256 bqs
    if (idx < 131072) {
        int head = idx >> 14;
        int q = (idx >> 6) & 255;
        int k = idx & 63;
        int qi = q >> 4, qj = q & 15;
        int ki = k >> 3, kj = k & 7;
        int r0 = qi - 2 * ki + 14, r1 = qj - 2 * kj + 14; // in [0,29]
        biasb[idx] = rel_table[(r0 * 30 + r1) * 8 + head];
    } else if (idx < 131328) {
        int i = idx - 131072;
        bqs[i] = bq[i] * ATT_SCALE;
    }
}

// pack mask -> one uint64 per (head,win,q) row: 33.5 MB int32 -> 1 MB bits
__global__ void prep_mask(const int* __restrict__ mask, unsigned long long* __restrict__ mp) {
    int idx = blockIdx.x * 256 + threadIdx.x;            // 131072 rows
    const int4* src = reinterpret_cast<const int4*>(mask + (size_t)idx * 64);
    unsigned long long bits = 0;
#pragma unroll
    for (int c = 0; c < 16; ++c) {
        int4 v = src[c];
        if (v.x) bits |= 1ull << (c * 4 + 0);
        if (v.y) bits |= 1ull << (c * 4 + 1);
        if (v.z) bits |= 1ull << (c * 4 + 2);
        if (v.w) bits |= 1ull << (c * 4 + 3);
    }
    mp[idx] = bits;
}

// ---------------------------------------------------------------------------
// GEMM: C[M][N] = A[M][K] * B + bias.  B given as B^T row-major bf16 [N][K].
// 128x128 tile, BK=32, 4 waves (2x2). mfma_f32_16x16x32_bf16.
// ---------------------------------------------------------------------------
template <typename InT, bool OUT_BF16>
__global__ __launch_bounds__(256) void gemm_proj(
    const InT* __restrict__ A, const unsigned short* __restrict__ BT,
    const float* __restrict__ bias, void* __restrict__ Cout,
    int M, int N, int K)
{
    __shared__ __align__(16) unsigned short As[128][40];
    __shared__ __align__(16) unsigned short Bs[128][40];

    const int tid = threadIdx.x;
    const int mb = blockIdx.y * 128;
    const int nb = blockIdx.x * 128;
    const int w = tid >> 6, lane = tid & 63, lr = lane & 15, lg = lane >> 4;
    const int wm = (w >> 1) * 64, wn = (w & 1) * 64;

    f32x4 acc[4][4];
#pragma unroll
    for (int i = 0; i < 4; ++i)
#pragma unroll
        for (int j = 0; j < 4; ++j) acc[i][j] = {0.f, 0.f, 0.f, 0.f};

    for (int kb = 0; kb < K; kb += 32) {
        if constexpr (std::is_same<InT, float>::value) {
#pragma unroll
            for (int i = 0; i < 4; ++i) {
                int row = (tid >> 3) + i * 32;
                int c4 = (tid & 7) * 4;
                const float4 v = *reinterpret_cast<const float4*>(
                    &A[(size_t)(mb + row) * K + kb + c4]);
                ushort4v u = { f2bf(v.x), f2bf(v.y), f2bf(v.z), f2bf(v.w) };
                *reinterpret_cast<ushort4v*>(&As[row][c4]) = u;
            }
        } else {
#pragma unroll
            for (int i = 0; i < 2; ++i) {
                int flat = tid + i * 256;
                int row = flat >> 2, c8 = (flat & 3) * 8;
                ushort8v v = *reinterpret_cast<const ushort8v*>(
                    &A[(size_t)(mb + row) * K + kb + c8]);
                *reinterpret_cast<ushort8v*>(&As[row][c8]) = v;
            }
        }
#pragma unroll
        for (int i = 0; i < 2; ++i) {
            int flat = tid + i * 256;
            int row = flat >> 2, c8 = (flat & 3) * 8;
            ushort8v v = *reinterpret_cast<const ushort8v*>(
                &BT[(size_t)(nb + row) * K + kb + c8]);
            *reinterpret_cast<ushort8v*>(&Bs[row][c8]) = v;
        }
        __syncthreads();

        short8v af[4], bfr[4];
#pragma unroll
        for (int mt = 0; mt < 4; ++mt)
            af[mt] = *reinterpret_cast<const short8v*>(&As[wm + mt * 16 + lr][lg * 8]);
#pragma unroll
        for (int nt = 0; nt < 4; ++nt)
            bfr[nt] = *reinterpret_cast<const short8v*>(&Bs[wn + nt * 16 + lr][lg * 8]);
#pragma unroll
        for (int mt = 0; mt < 4; ++mt)
#pragma unroll
            for (int nt = 0; nt < 4; ++nt)
                acc[mt][nt] = __builtin_amdgcn_mfma_f32_16x16x32_bf16(
                    af[mt], bfr[nt], acc[mt][nt], 0, 0, 0);
        __syncthreads();
    }

#pragma unroll
    for (int mt = 0; mt < 4; ++mt)
#pragma unroll
        for (int nt = 0; nt < 4; ++nt)
#pragma unroll
            for (int j = 0; j < 4; ++j) {
                int row = mb + wm + mt * 16 + lg * 4 + j;
                int col = nb + wn + nt * 16 + lr;
                float v = acc[mt][nt][j] + bias[col];
                if constexpr (OUT_BF16)
                    ((unsigned short*)Cout)[(size_t)row * N + col] = f2bf(v);
                else
                    ((float*)Cout)[(size_t)row * N + col] = v;
            }
}

// ---------------------------------------------------------------------------
// Fused window attention, v2. One block = (b, window, head), 256 thr, 4 waves.
// Q/K MFMA fragments loaded DIRECTLY global->reg (16B contiguous per lane) —
// no Q/K LDS staging, no staging barrier. LDS: XOR-swizzled P (32KB) + Vt
// (4.6KB) = 37.4KB -> 4 blocks/CU. Single __syncthreads (Vt + Ps ordering).
// Mask via packed uint64 per q-row; 1/sqrt(dk) pre-folded into Wq.
// ---------------------------------------------------------------------------
__global__ __launch_bounds__(256) void win_attn(
    unsigned short* __restrict__ Qbuf,            // [8*128*128, 256] bf16 (in/out)
    const unsigned short* __restrict__ KVbuf,     // [8*64*64, 512] bf16
    const unsigned long long* __restrict__ maskp, // [8][64][256] packed bits
    const float* __restrict__ biasb)              // [8][256][64]
{
    __shared__ __align__(16) unsigned char Pb[256 * 128];   // P, 64-wide XOR-swizzled
    __shared__ __align__(16) unsigned short Vt[32][72];     // V^T: [dk][key]

    const int tid = threadIdx.x;
    const int win = blockIdx.x, head = blockIdx.y, b = blockIdx.z;
    const int wi = win >> 3, wj = win & 7;
    const int w = tid >> 6, lane = tid & 63, lr = lane & 15, lg = lane >> 4;
    const int qb = w * 64;

    // ---- stage V transposed (all 256 threads, 16B load + 8 scalar LDS writes)
    {
        int key = tid & 63, c = tid >> 6;
        int kr = (wi * 8 + (key >> 3) + 4) & 63;
        int kc = (wj * 8 + (key & 7) + 4) & 63;
        ushort8v v = *reinterpret_cast<const ushort8v*>(
            KVbuf + ((size_t)(b * 4096 + kr * 64 + kc)) * 512 + 256 + head * 32 + c * 8);
#pragma unroll
        for (int e = 0; e < 8; ++e) Vt[c * 8 + e][key] = v[e];
    }

    // ---- Q and K fragments: direct global loads (16B contiguous per lane) --
    short8v qf[4], kf[4];
#pragma unroll
    for (int mt = 0; mt < 4; ++mt) {
        int q = qb + mt * 16 + lr;
        int gr = (wi * 16 + (q >> 4) + 8) & 127;
        int gc = (wj * 16 + (q & 15) + 8) & 127;
        qf[mt] = *reinterpret_cast<const short8v*>(
            Qbuf + ((size_t)(b * 16384 + gr * 128 + gc)) * 256 + head * 32 + lg * 8);
    }
#pragma unroll
    for (int nt = 0; nt < 4; ++nt) {
        int key = nt * 16 + lr;
        int kr = (wi * 8 + (key >> 3) + 4) & 63;
        int kc = (wj * 8 + (key & 7) + 4) & 63;
        kf[nt] = *reinterpret_cast<const short8v*>(
            KVbuf + ((size_t)(b * 4096 + kr * 64 + kc)) * 512 + head * 32 + lg * 8);
    }

    // ---- S = Q K^T (scale pre-folded into Wq) ----
    f32x4 s[4][4];
#pragma unroll
    for (int mt = 0; mt < 4; ++mt)
#pragma unroll
        for (int nt = 0; nt < 4; ++nt) s[mt][nt] = {0.f, 0.f, 0.f, 0.f};
    __builtin_amdgcn_s_setprio(1);
#pragma unroll
    for (int mt = 0; mt < 4; ++mt)
#pragma unroll
        for (int nt = 0; nt < 4; ++nt)
            s[mt][nt] = __builtin_amdgcn_mfma_f32_16x16x32_bf16(qf[mt], kf[nt], s[mt][nt], 0, 0, 0);
    __builtin_amdgcn_s_setprio(0);

    // ---- bias + mask + softmax; P -> swizzled LDS ----
    const unsigned long long* mrow = maskp + (size_t)(head * 64 + win) * 256;
#pragma unroll
    for (int mt = 0; mt < 4; ++mt) {
#pragma unroll
        for (int j = 0; j < 4; ++j) {
            int q = qb + mt * 16 + lg * 4 + j;
            unsigned long long mb = mrow[q];
            const float* brow = biasb + (size_t)(head * 256 + q) * 64;
            float v[4];
            float m = -3.0e38f;
#pragma unroll
            for (int nt = 0; nt < 4; ++nt) {
                int key = nt * 16 + lr;
                float sv = s[mt][nt][j] + brow[key];
                if ((mb >> key) & 1ull) sv = -1.0e9f;
                v[nt] = sv;
                m = fmaxf(m, sv);
            }
#pragma unroll
            for (int d = 1; d < 16; d <<= 1) m = fmaxf(m, __shfl_xor(m, d, 64));
            float sum = 0.f;
#pragma unroll
            for (int nt = 0; nt < 4; ++nt) { v[nt] = __expf(v[nt] - m); sum += v[nt]; }
#pragma unroll
            for (int d = 1; d < 16; d <<= 1) sum += __shfl_xor(sum, d, 64);
            float inv = 1.0f / sum;
            int sw = (q & 7) << 4;
#pragma unroll
            for (int nt = 0; nt < 4; ++nt) {
                int off = q * 128 + (((nt * 16 + lr) * 2) ^ sw);
                *reinterpret_cast<unsigned short*>(Pb + off) = f2bf(v[nt] * inv);
            }
        }
    }

    __syncthreads();   // Vt writes + Ps writes visible to all waves

    // ---- O = P V : K=64 in 2 chunks via V^T ----
    f32x4 o[4][2];
#pragma unroll
    for (int mt = 0; mt < 4; ++mt)
#pragma unroll
        for (int nt = 0; nt < 2; ++nt) o[mt][nt] = {0.f, 0.f, 0.f, 0.f};
#pragma unroll
    for (int kc = 0; kc < 2; ++kc) {
        short8v pf[4], vf[2];
#pragma unroll
        for (int mt = 0; mt < 4; ++mt) {
            int row = qb + mt * 16 + lr;
            int coff = (kc * 64 + lg * 16) ^ ((row & 7) << 4);
            pf[mt] = *reinterpret_cast<const short8v*>(Pb + row * 128 + coff);
        }
#pragma unroll
        for (int nt = 0; nt < 2; ++nt)
            vf[nt] = *reinterpret_cast<const short8v*>(&Vt[nt * 16 + lr][kc * 32 + lg * 8]);
        __builtin_amdgcn_s_setprio(1);
#pragma unroll
        for (int mt = 0; mt < 4; ++mt)
#pragma unroll
            for (int nt = 0; nt < 2; ++nt)
                o[mt][nt] = __builtin_amdgcn_mfma_f32_16x16x32_bf16(pf[mt], vf[nt], o[mt][nt], 0, 0, 0);
        __builtin_amdgcn_s_setprio(0);
    }

    // ---- store O in-place into Qbuf ----
#pragma unroll
    for (int mt = 0; mt < 4; ++mt)
#pragma unroll
        for (int j = 0; j < 4; ++j) {
            int q = qb + mt * 16 + lg * 4 + j;
            int gr = (wi * 16 + (q >> 4) + 8) & 127;
            int gc = (wj * 16 + (q & 15) + 8) & 127;
            unsigned short* dst =
                Qbuf + ((size_t)(b * 16384 + gr * 128 + gc)) * 256 + head * 32;
#pragma unroll
            for (int nt = 0; nt < 2; ++nt)
                dst[nt * 16 + lr] = f2bf(o[mt][nt][j]);
        }
}

// ---------------------------------------------------------------------------
extern "C" void kernel_launch(void* const* d_in, const int* in_sizes, int n_in,
                              void* d_out, int out_size, void* d_ws, size_t ws_size,
                              hipStream_t stream) {
    const float* x    = (const float*)d_in[0];
    const float* z    = (const float*)d_in[1];
    const int*   mask = (const int*)d_in[2];
    const float* Wq   = (const float*)d_in[3];
    const float* bq   = (const float*)d_in[4];
    const float* Wkv  = (const float*)d_in[5];
    const float* bkv  = (const float*)d_in[6];
    const float* Wo   = (const float*)d_in[7];
    const float* bo   = (const float*)d_in[8];
    const float* rel  = (const float*)d_in[9];
    float* out = (float*)d_out;

    // workspace layout (~103 MB)
    char* ws = (char*)d_ws;
    unsigned short*     Qbuf  = (unsigned short*)(ws);                 // 67,108,864 B
    unsigned short*     KVbuf = (unsigned short*)(ws + 67108864);      // 33,554,432 B
    unsigned short*     WqT   = (unsigned short*)(ws + 100663296);     //    131,072 B
    unsigned short*     WkvT  = (unsigned short*)(ws + 100794368);     //    262,144 B
    unsigned short*     WoT   = (unsigned short*)(ws + 101056512);     //    131,072 B
    float*              biasb = (float*)(ws + 101187584);              //    524,288 B
    unsigned long long* maskp = (unsigned long long*)(ws + 101711872); //  1,048,576 B
    float*              bqs   = (float*)(ws + 102760448);              //      1,024 B

    prep_weights<<<1024, 256, 0, stream>>>(Wq, Wkv, Wo, WqT, WkvT, WoT);
    prep_bias<<<513, 256, 0, stream>>>(rel, bq, biasb, bqs);
    prep_mask<<<512, 256, 0, stream>>>(mask, maskp);

    // Q = x @ (Wq*scale) + bq*scale  -> bf16 [131072, 256]
    gemm_proj<float, true><<<dim3(2, 1024), 256, 0, stream>>>(
        x, WqT, bqs, (void*)Qbuf, 131072, 256, 256);
    // KV = z @ Wkv + bkv -> bf16 [32768, 512]
    gemm_proj<float, true><<<dim3(4, 256), 256, 0, stream>>>(
        z, WkvT, bkv, (void*)KVbuf, 32768, 512, 256);
    // fused window attention (in-place into Qbuf)
    win_attn<<<dim3(64, 8, 8), 256, 0, stream>>>(Qbuf, KVbuf, maskp, biasb);
    // out = attn @ Wo + bo -> f32
    gemm_proj<unsigned short, false><<<dim3(2, 1024), 256, 0, stream>>>(
        Qbuf, WoT, bo, (void*)out, 131072, 256, 256);
}

// Round 3
// 221.292 us; speedup vs baseline: 1.0223x; 1.0036x over previous
//
#include <hip/hip_runtime.h>
#include <hip/hip_bf16.h>
#include <type_traits>

// ---------------------------------------------------------------------------
// Problem constants
//   x: (8,128,128,256) f32   z: (8,64,64,256) f32   mask: (1,8,8,8,256,64) int
//   Wq (256,256) bq(256)  Wkv (256,512) bkv(512)  Wo (256,256) bo(256)
//   rel_table (900,8) f32   out: (8,128,128,256) f32
// ---------------------------------------------------------------------------

typedef __attribute__((ext_vector_type(8))) short short8v;     // MFMA bf16 frag (4 VGPR)
typedef __attribute__((ext_vector_type(4))) float f32x4;       // MFMA acc
typedef __attribute__((ext_vector_type(8))) unsigned short ushort8v;
typedef __attribute__((ext_vector_type(4))) unsigned short ushort4v;

#define DEV __device__ __forceinline__

DEV unsigned short f2bf(float f) {               // round-to-nearest-even f32->bf16
    union { float f; unsigned u; } v; v.f = f;
    unsigned r = v.u + 0x7FFFu + ((v.u >> 16) & 1u);
    return (unsigned short)(r >> 16);
}

#define ATT_SCALE 0.17677669529663687f           // 1/sqrt(32)

// ---------------------------------------------------------------------------
// Prep kernels (unchanged from R1)
// ---------------------------------------------------------------------------
__global__ void prep_weights(const float* __restrict__ Wq, const float* __restrict__ Wkv,
                             const float* __restrict__ Wo,
                             unsigned short* __restrict__ WqT, unsigned short* __restrict__ WkvT,
                             unsigned short* __restrict__ WoT) {
    int idx = blockIdx.x * 256 + threadIdx.x;            // 262144 total
    if (idx < 65536) {
        int n = idx >> 8, k = idx & 255;
        WqT[idx] = f2bf(Wq[k * 256 + n] * ATT_SCALE);
    } else if (idx < 196608) {
        int i = idx - 65536;
        int n = i >> 8, k = i & 255;
        WkvT[i] = f2bf(Wkv[k * 512 + n]);
    } else {
        int i = idx - 196608;
        int n = i >> 8, k = i & 255;
        WoT[i] = f2bf(Wo[k * 256 + n]);
    }
}

__global__ void prep_bias(const float* __restrict__ rel_table, const float* __restrict__ bq,
                          float* __restrict__ biasb, float* __restrict__ bqs) {
    int idx = blockIdx.x * 256 + threadIdx.x;
    if (idx < 131072) {
        int head = idx >> 14;
        int q = (idx >> 6) & 255;
        int k = idx & 63;
        int qi = q >> 4, qj = q & 15;
        int ki = k >> 3, kj = k & 7;
        int r0 = qi - 2 * ki + 14, r1 = qj - 2 * kj + 14;
        biasb[idx] = rel_table[(r0 * 30 + r1) * 8 + head];
    } else if (idx < 131328) {
        int i = idx - 131072;
        bqs[i] = bq[i] * ATT_SCALE;
    }
}

__global__ void prep_mask(const int* __restrict__ mask, unsigned long long* __restrict__ mp) {
    int idx = blockIdx.x * 256 + threadIdx.x;            // 131072 rows
    const int4* src = reinterpret_cast<const int4*>(mask + (size_t)idx * 64);
    unsigned long long bits = 0;
#pragma unroll
    for (int c = 0; c < 16; ++c) {
        int4 v = src[c];
        if (v.x) bits |= 1ull << (c * 4 + 0);
        if (v.y) bits |= 1ull << (c * 4 + 1);
        if (v.z) bits |= 1ull << (c * 4 + 2);
        if (v.w) bits |= 1ull << (c * 4 + 3);
    }
    mp[idx] = bits;
}

// ---------------------------------------------------------------------------
// GEMM v2: C[M][N] = A[M][K]*B + bias, B^T row-major bf16 [N][K].
// 128x128 tile, BK=32, 4 waves (2x2), double-buffered LDS, ONE barrier/step.
// B (and A when bf16) staged via global_load_lds width=16 into LINEAR LDS
// with pre-swizzled per-lane global source (slot s = sp ^ ((r>>1)&3));
// ds_read applies the same XOR -> bank-floor-optimal b128 reads.
// A-f32 reg-staged (T14 split: load early, convert+ds_write after MFMA).
// ---------------------------------------------------------------------------
template <bool AF32, bool OUT_BF16>
__global__ __launch_bounds__(256) void gemm_proj(
    const void* __restrict__ Ain, const unsigned short* __restrict__ BT,
    const float* __restrict__ bias, void* __restrict__ Cout,
    int M, int N, int K)
{
    __shared__ __align__(16) unsigned char As[2][8192];   // 128 rows x 64B (32 bf16)
    __shared__ __align__(16) unsigned char Bs[2][8192];
    const float* Af = (const float*)Ain;
    const unsigned short* Ab = (const unsigned short*)Ain;

    const int tid = threadIdx.x;
    const int mb = blockIdx.y * 128, nb = blockIdx.x * 128;
    const int w = tid >> 6, lane = tid & 63, lr = lane & 15, lg = lane >> 4;
    const int wm = (w >> 1) * 64, wn = (w & 1) * 64;

    // per-lane staging coords for global_load_lds (wave w covers rows 32w..32w+31)
    const int cr0 = (w << 5) + (lane >> 2);          // chunk0 row
    const int csp = lane & 3;                        // LDS slot this lane fills
    const int cs0 = csp ^ ((cr0 >> 1) & 3);          // global slot fetched (chunk0)
    const int cs1 = csp ^ (((cr0 + 16) >> 1) & 3);   // chunk1

    // B stage: 2 x 1KB global_load_lds per wave
    auto stageB = [&](int buf, int kb) {
        __builtin_amdgcn_global_load_lds(
            (const __attribute__((address_space(1))) void*)(BT + (size_t)(nb + cr0) * K + kb + cs0 * 8),
            (__attribute__((address_space(3))) void*)(&Bs[buf][w << 11]), 16, 0, 0);
        __builtin_amdgcn_global_load_lds(
            (const __attribute__((address_space(1))) void*)(BT + (size_t)(nb + cr0 + 16) * K + kb + cs1 * 8),
            (__attribute__((address_space(3))) void*)(&Bs[buf][(w << 11) + 1024]), 16, 0, 0);
    };
    auto stageA_lds = [&](int buf, int kb) {         // A bf16 path
        __builtin_amdgcn_global_load_lds(
            (const __attribute__((address_space(1))) void*)(Ab + (size_t)(mb + cr0) * K + kb + cs0 * 8),
            (__attribute__((address_space(3))) void*)(&As[buf][w << 11]), 16, 0, 0);
        __builtin_amdgcn_global_load_lds(
            (const __attribute__((address_space(1))) void*)(Ab + (size_t)(mb + cr0 + 16) * K + kb + cs1 * 8),
            (__attribute__((address_space(3))) void*)(&As[buf][(w << 11) + 1024]), 16, 0, 0);
    };

    // A f32 path: reg-stage (2 slots/thread: 2x float4 each), convert+write late
    float4 areg[2][2];
    auto loadA = [&](int kb) {
#pragma unroll
        for (int i = 0; i < 2; ++i) {
            int flat = tid + (i << 8);
            int r = flat >> 2, sp = flat & 3;
            int s = sp ^ ((r >> 1) & 3);
            const float* src = Af + (size_t)(mb + r) * K + kb + s * 8;
            areg[i][0] = *reinterpret_cast<const float4*>(src);
            areg[i][1] = *reinterpret_cast<const float4*>(src + 4);
        }
    };
    auto writeA = [&](int buf) {
#pragma unroll
        for (int i = 0; i < 2; ++i) {
            int flat = tid + (i << 8);
            int r = flat >> 2, sp = flat & 3;
            ushort8v u = { f2bf(areg[i][0].x), f2bf(areg[i][0].y),
                           f2bf(areg[i][0].z), f2bf(areg[i][0].w),
                           f2bf(areg[i][1].x), f2bf(areg[i][1].y),
                           f2bf(areg[i][1].z), f2bf(areg[i][1].w) };
            *reinterpret_cast<ushort8v*>(&As[buf][r * 64 + sp * 16]) = u;
        }
    };

    auto rdA = [&](int buf, int row) -> short8v {
        int swz = (lg ^ ((row >> 1) & 3)) << 4;
        return *reinterpret_cast<const short8v*>(&As[buf][row * 64 + swz]);
    };
    auto rdB = [&](int buf, int row) -> short8v {
        int swz = (lg ^ ((row >> 1) & 3)) << 4;
        return *reinterpret_cast<const short8v*>(&Bs[buf][row * 64 + swz]);
    };

    f32x4 acc[4][4];
#pragma unroll
    for (int i = 0; i < 4; ++i)
#pragma unroll
        for (int j = 0; j < 4; ++j) acc[i][j] = {0.f, 0.f, 0.f, 0.f};

    // ---- prologue: stage tile 0 ----
    if constexpr (AF32) { loadA(0); stageB(0, 0); writeA(0); }
    else               { stageA_lds(0, 0); stageB(0, 0); }
    __syncthreads();                     // compiler drains vmcnt before barrier

    const int NT = K >> 5;
    int cur = 0;
    for (int t = 0; t < NT; ++t) {
        // ---- issue next-tile loads first (latency hides under MFMA) ----
        if (t + 1 < NT) {
            if constexpr (AF32) { loadA((t + 1) << 5); stageB(cur ^ 1, (t + 1) << 5); }
            else { stageA_lds(cur ^ 1, (t + 1) << 5); stageB(cur ^ 1, (t + 1) << 5); }
        }
        // ---- compute current tile ----
        short8v af[4], bfr[4];
#pragma unroll
        for (int mt = 0; mt < 4; ++mt) af[mt] = rdA(cur, wm + mt * 16 + lr);
#pragma unroll
        for (int nt = 0; nt < 4; ++nt) bfr[nt] = rdB(cur, wn + nt * 16 + lr);
#pragma unroll
        for (int mt = 0; mt < 4; ++mt)
#pragma unroll
            for (int nt = 0; nt < 4; ++nt)
                acc[mt][nt] = __builtin_amdgcn_mfma_f32_16x16x32_bf16(
                    af[mt], bfr[nt], acc[mt][nt], 0, 0, 0);
        // ---- late half of A staging (regs -> LDS of NEXT buffer) ----
        if (t + 1 < NT) { if constexpr (AF32) writeA(cur ^ 1); }
        __syncthreads();
        cur ^= 1;
    }

    // ---- epilogue ----
#pragma unroll
    for (int mt = 0; mt < 4; ++mt)
#pragma unroll
        for (int nt = 0; nt < 4; ++nt)
#pragma unroll
            for (int j = 0; j < 4; ++j) {
                int row = mb + wm + mt * 16 + lg * 4 + j;
                int col = nb + wn + nt * 16 + lr;
                float v = acc[mt][nt][j] + bias[col];
                if constexpr (OUT_BF16)
                    ((unsigned short*)Cout)[(size_t)row * N + col] = f2bf(v);
                else
                    ((float*)Cout)[(size_t)row * N + col] = v;
            }
}

// ---------------------------------------------------------------------------
// Fused window attention (unchanged from R1).
// ---------------------------------------------------------------------------
__global__ __launch_bounds__(256) void win_attn(
    unsigned short* __restrict__ Qbuf,            // [8*128*128, 256] bf16 (in/out)
    const unsigned short* __restrict__ KVbuf,     // [8*64*64, 512] bf16
    const unsigned long long* __restrict__ maskp, // [8][64][256] packed bits
    const float* __restrict__ biasb)              // [8][256][64]
{
    __shared__ __align__(16) unsigned char Pb[256 * 128];   // P, 64-wide XOR-swizzled
    __shared__ __align__(16) unsigned short Vt[32][72];     // V^T: [dk][key]

    const int tid = threadIdx.x;
    const int win = blockIdx.x, head = blockIdx.y, b = blockIdx.z;
    const int wi = win >> 3, wj = win & 7;
    const int w = tid >> 6, lane = tid & 63, lr = lane & 15, lg = lane >> 4;
    const int qb = w * 64;

    {
        int key = tid & 63, c = tid >> 6;
        int kr = (wi * 8 + (key >> 3) + 4) & 63;
        int kc = (wj * 8 + (key & 7) + 4) & 63;
        ushort8v v = *reinterpret_cast<const ushort8v*>(
            KVbuf + ((size_t)(b * 4096 + kr * 64 + kc)) * 512 + 256 + head * 32 + c * 8);
#pragma unroll
        for (int e = 0; e < 8; ++e) Vt[c * 8 + e][key] = v[e];
    }

    short8v qf[4], kf[4];
#pragma unroll
    for (int mt = 0; mt < 4; ++mt) {
        int q = qb + mt * 16 + lr;
        int gr = (wi * 16 + (q >> 4) + 8) & 127;
        int gc = (wj * 16 + (q & 15) + 8) & 127;
        qf[mt] = *reinterpret_cast<const short8v*>(
            Qbuf + ((size_t)(b * 16384 + gr * 128 + gc)) * 256 + head * 32 + lg * 8);
    }
#pragma unroll
    for (int nt = 0; nt < 4; ++nt) {
        int key = nt * 16 + lr;
        int kr = (wi * 8 + (key >> 3) + 4) & 63;
        int kc = (wj * 8 + (key & 7) + 4) & 63;
        kf[nt] = *reinterpret_cast<const short8v*>(
            KVbuf + ((size_t)(b * 4096 + kr * 64 + kc)) * 512 + head * 32 + lg * 8);
    }

    f32x4 s[4][4];
#pragma unroll
    for (int mt = 0; mt < 4; ++mt)
#pragma unroll
        for (int nt = 0; nt < 4; ++nt) s[mt][nt] = {0.f, 0.f, 0.f, 0.f};
    __builtin_amdgcn_s_setprio(1);
#pragma unroll
    for (int mt = 0; mt < 4; ++mt)
#pragma unroll
        for (int nt = 0; nt < 4; ++nt)
            s[mt][nt] = __builtin_amdgcn_mfma_f32_16x16x32_bf16(qf[mt], kf[nt], s[mt][nt], 0, 0, 0);
    __builtin_amdgcn_s_setprio(0);

    const unsigned long long* mrow = maskp + (size_t)(head * 64 + win) * 256;
#pragma unroll
    for (int mt = 0; mt < 4; ++mt) {
#pragma unroll
        for (int j = 0; j < 4; ++j) {
            int q = qb + mt * 16 + lg * 4 + j;
            unsigned long long mb = mrow[q];
            const float* brow = biasb + (size_t)(head * 256 + q) * 64;
            float v[4];
            float m = -3.0e38f;
#pragma unroll
            for (int nt = 0; nt < 4; ++nt) {
                int key = nt * 16 + lr;
                float sv = s[mt][nt][j] + brow[key];
                if ((mb >> key) & 1ull) sv = -1.0e9f;
                v[nt] = sv;
                m = fmaxf(m, sv);
            }
#pragma unroll
            for (int d = 1; d < 16; d <<= 1) m = fmaxf(m, __shfl_xor(m, d, 64));
            float sum = 0.f;
#pragma unroll
            for (int nt = 0; nt < 4; ++nt) { v[nt] = __expf(v[nt] - m); sum += v[nt]; }
#pragma unroll
            for (int d = 1; d < 16; d <<= 1) sum += __shfl_xor(sum, d, 64);
            float inv = 1.0f / sum;
            int sw = (q & 7) << 4;
#pragma unroll
            for (int nt = 0; nt < 4; ++nt) {
                int off = q * 128 + (((nt * 16 + lr) * 2) ^ sw);
                *reinterpret_cast<unsigned short*>(Pb + off) = f2bf(v[nt] * inv);
            }
        }
    }

    __syncthreads();

    f32x4 o[4][2];
#pragma unroll
    for (int mt = 0; mt < 4; ++mt)
#pragma unroll
        for (int nt = 0; nt < 2; ++nt) o[mt][nt] = {0.f, 0.f, 0.f, 0.f};
#pragma unroll
    for (int kc = 0; kc < 2; ++kc) {
        short8v pf[4], vf[2];
#pragma unroll
        for (int mt = 0; mt < 4; ++mt) {
            int row = qb + mt * 16 + lr;
            int coff = (kc * 64 + lg * 16) ^ ((row & 7) << 4);
            pf[mt] = *reinterpret_cast<const short8v*>(Pb + row * 128 + coff);
        }
#pragma unroll
        for (int nt = 0; nt < 2; ++nt)
            vf[nt] = *reinterpret_cast<const short8v*>(&Vt[nt * 16 + lr][kc * 32 + lg * 8]);
        __builtin_amdgcn_s_setprio(1);
#pragma unroll
        for (int mt = 0; mt < 4; ++mt)
#pragma unroll
            for (int nt = 0; nt < 2; ++nt)
                o[mt][nt] = __builtin_amdgcn_mfma_f32_16x16x32_bf16(pf[mt], vf[nt], o[mt][nt], 0, 0, 0);
        __builtin_amdgcn_s_setprio(0);
    }

#pragma unroll
    for (int mt = 0; mt < 4; ++mt)
#pragma unroll
        for (int j = 0; j < 4; ++j) {
            int q = qb + mt * 16 + lg * 4 + j;
            int gr = (wi * 16 + (q >> 4) + 8) & 127;
            int gc = (wj * 16 + (q & 15) + 8) & 127;
            unsigned short* dst =
                Qbuf + ((size_t)(b * 16384 + gr * 128 + gc)) * 256 + head * 32;
#pragma unroll
            for (int nt = 0; nt < 2; ++nt)
                dst[nt * 16 + lr] = f2bf(o[mt][nt][j]);
        }
}

// ---------------------------------------------------------------------------
extern "C" void kernel_launch(void* const* d_in, const int* in_sizes, int n_in,
                              void* d_out, int out_size, void* d_ws, size_t ws_size,
                              hipStream_t stream) {
    const float* x    = (const float*)d_in[0];
    const float* z    = (const float*)d_in[1];
    const int*   mask = (const int*)d_in[2];
    const float* Wq   = (const float*)d_in[3];
    const float* bq   = (const float*)d_in[4];
    const float* Wkv  = (const float*)d_in[5];
    const float* bkv  = (const float*)d_in[6];
    const float* Wo   = (const float*)d_in[7];
    const float* bo   = (const float*)d_in[8];
    const float* rel  = (const float*)d_in[9];
    float* out = (float*)d_out;

    // workspace layout (~103 MB)
    char* ws = (char*)d_ws;
    unsigned short*     Qbuf  = (unsigned short*)(ws);                 // 67,108,864 B
    unsigned short*     KVbuf = (unsigned short*)(ws + 67108864);      // 33,554,432 B
    unsigned short*     WqT   = (unsigned short*)(ws + 100663296);     //    131,072 B
    unsigned short*     WkvT  = (unsigned short*)(ws + 100794368);     //    262,144 B
    unsigned short*     WoT   = (unsigned short*)(ws + 101056512);     //    131,072 B
    float*              biasb = (float*)(ws + 101187584);              //    524,288 B
    unsigned long long* maskp = (unsigned long long*)(ws + 101711872); //  1,048,576 B
    float*              bqs   = (float*)(ws + 102760448);              //      1,024 B

    prep_weights<<<1024, 256, 0, stream>>>(Wq, Wkv, Wo, WqT, WkvT, WoT);
    prep_bias<<<513, 256, 0, stream>>>(rel, bq, biasb, bqs);
    prep_mask<<<512, 256, 0, stream>>>(mask, maskp);

    // Q = x @ (Wq*scale) + bq*scale  -> bf16 [131072, 256]
    gemm_proj<true, true><<<dim3(2, 1024), 256, 0, stream>>>(
        (const void*)x, WqT, bqs, (void*)Qbuf, 131072, 256, 256);
    // KV = z @ Wkv + bkv -> bf16 [32768, 512]
    gemm_proj<true, true><<<dim3(4, 256), 256, 0, stream>>>(
        (const void*)z, WkvT, bkv, (void*)KVbuf, 32768, 512, 256);
    // fused window attention (in-place into Qbuf)
    win_attn<<<dim3(64, 8, 8), 256, 0, stream>>>(Qbuf, KVbuf, maskp, biasb);
    // out = attn @ Wo + bo -> f32
    gemm_proj<false, false><<<dim3(2, 1024), 256, 0, stream>>>(
        (const void*)Qbuf, WoT, bo, (void*)out, 131072, 256, 256);
}